// Round 2
// baseline (320.394 us; speedup 1.0000x reference)
//
#include <hip/hip_runtime.h>
#include <hip/hip_bf16.h>
#include <stdint.h>

#define B_ 4
#define H_ 16
#define S_ 2048
#define D_ 64
#define NKT (S_ / 64)
#define QM 128

typedef __attribute__((ext_vector_type(8))) short bf16x8;
typedef __attribute__((ext_vector_type(4))) float f32x4;
typedef unsigned long long u64;
typedef unsigned int u32;

__device__ inline short f2bf(float f) {
  union { float f; u32 u; } x; x.f = f;
  u32 r = x.u + 0x7FFFu + ((x.u >> 16) & 1u);
  return (short)(r >> 16);
}
__device__ inline short4 f2bf4(float4 v) {
  short4 s; s.x = f2bf(v.x); s.y = f2bf(v.y); s.z = f2bf(v.z); s.w = f2bf(v.w);
  return s;
}

// XOR-swizzled byte offset in a row x 128-byte tile image
__device__ inline int SW(int row, int byteoff) {
  return row * 128 + (byteoff ^ ((row & 7) << 4));
}

__device__ inline void gll16(const void* g, void* l) {
  __builtin_amdgcn_global_load_lds(
      (const __attribute__((address_space(1))) u32*)g,
      (__attribute__((address_space(3))) u32*)(uintptr_t)l, 16, 0, 0);
}

// ---------------- fused prepass (unchanged) ----------------
// blocks [0,8192):        K fp32 -> bf16 swizzled rows
// blocks [8192,10240):    V fp32 -> bf16 transposed 64-key tiles (2048 tiles)
// blocks [10240,26624):   mask int32 -> packed u64 bits
__global__ __launch_bounds__(256)
void prepass(const float* __restrict__ Kg, const float* __restrict__ Vg,
             const int* __restrict__ Mg,
             char* __restrict__ Ksw, char* __restrict__ Vsw, u64* __restrict__ Mp) {
  __shared__ short tile[4096];
  const int bid = blockIdx.x, tid = threadIdx.x;
  if (bid < 8192) {
    int idx = bid * 256 + tid;
    int row = idx >> 4, c4 = idx & 15;
    float4 v = *(const float4*)(Kg + (size_t)idx * 4);
    *(short4*)(Ksw + (size_t)row * 128 + ((c4 * 8) ^ ((row & 7) << 4))) = f2bf4(v);
  } else if (bid < 10240) {
    int vb = bid - 8192;
    char* ct = (char*)tile;
    int c4 = tid & 15, g = tid >> 4;
    const float* src = Vg + (size_t)vb * (64 * D_) + (size_t)(g * 4) * D_ + c4 * 4;
    float4 vv[4];
#pragma unroll
    for (int i = 0; i < 4; ++i) vv[i] = *(const float4*)(src + (size_t)i * D_);
    const float* vf = (const float*)vv;
#pragma unroll
    for (int dd = 0; dd < 4; ++dd) {
      short4 s;
      s.x = f2bf(vf[0 * 4 + dd]);
      s.y = f2bf(vf[1 * 4 + dd]);
      s.z = f2bf(vf[2 * 4 + dd]);
      s.w = f2bf(vf[3 * 4 + dd]);
      *(short4*)(ct + SW(c4 * 4 + dd, g * 8)) = s;
    }
    __syncthreads();
    char* dst = Vsw + (size_t)vb * 8192;
#pragma unroll
    for (int j = 0; j < 2; ++j)
      *(float4*)(dst + tid * 16 + j * 4096) = *(const float4*)(ct + tid * 16 + j * 4096);
  } else {
    int pb = bid - 10240;
    int gbase = pb * 1024;
#pragma unroll
    for (int j = 0; j < 4; ++j) {
      int idx = gbase + j * 256 + tid;
      u64 bits = __ballot(Mg[idx] != 0);
      if ((tid & 63) == 0) Mp[idx >> 6] = bits;
    }
  }
}

// ---------------- main kernel ----------------
// Swapped-operand QK^T (computes S^T) so each lane owns a full 16-key slice of ONE
// q-row; P -> PV A-fragment transform is fully in-register:
//   For X = pk[2t][h], Y = pk[2t+1][h]:
//     permlane32_swap(vdst=X, vsrc=Y)  ->  X=[X0,X1,Y0,Y1], Y=[X2,X3,Y2,Y3]
//     permlane16_swap(vdst=X, vsrc=Y)  ->  X=[X0,X2,Y0,Y2]=W_A, Y=[X1,X3,Y1,Y3]=W_B
//   uw[h] = X (keys 32t+8q+2h), uw[2+h] = Y (keys 32t+8q+4+2h).   (role order verified)
// No LDS strip, no barrier B. LDS 32 KiB -> 4 blocks/CU; grid 1024 = one full round.
__global__ __launch_bounds__(256, 4)
void attn_kernel(const float* __restrict__ Qg,
                 const char* __restrict__ Ksw,
                 const char* __restrict__ Vsw,
                 const u64* __restrict__ Mp,
                 float* __restrict__ Og) {
  __shared__ short sK[2][4096];
  __shared__ short sV[2][4096];

  const int tid  = threadIdx.x;
  const int w    = tid >> 6;
  const int lane = tid & 63;
  const int quad = lane >> 4;
  const int c    = lane & 15;
  const int bh   = blockIdx.y;
  const int b    = bh >> 4;            // H_ == 16
  const int q0   = blockIdx.x * QM;
  const size_t base = (size_t)bh * (S_ * D_);
  const char* Kt = Ksw + (size_t)bh * (S_ * 128);
  const char* Vt = Vsw + (size_t)bh * (S_ * 128);
  char* cK0 = (char*)sK;               // 16 KB contiguous, doubles as Q stage

  // ---- stage Q (pre-scaled into log2 domain) into the sK area ----
  const float SC = 0.125f * 1.44269504088896f;   // 1/sqrt(64) * log2(e)
#pragma unroll
  for (int j = 0; j < 8; ++j) {
    int idx = tid + j * 256;
    int row = idx >> 4, c4 = idx & 15;
    float4 v = *(const float4*)(Qg + base + (size_t)(q0 + row) * D_ + c4 * 4);
    v.x *= SC; v.y *= SC; v.z *= SC; v.w *= SC;
    *(short4*)(cK0 + SW(row, c4 * 8)) = f2bf4(v);
  }
  __syncthreads();
  bf16x8 qa[2][2];
#pragma unroll
  for (int gi = 0; gi < 2; ++gi) {
    qa[gi][0] = *(bf16x8*)(cK0 + SW(32 * w + 16 * gi + c, quad * 16));
    qa[gi][1] = *(bf16x8*)(cK0 + SW(32 * w + 16 * gi + c, 64 + quad * 16));
  }
  __syncthreads();   // all Q reads done; sK area may now be overwritten

  // issue tile-0 async staging
#pragma unroll
  for (int j = 0; j < 2; ++j) {
    gll16(Kt + tid * 16 + j * 4096, (char*)sK[0] + tid * 16 + j * 4096);
    gll16(Vt + tid * 16 + j * 4096, (char*)sV[0] + tid * 16 + j * 4096);
  }

  f32x4 acco[2][4];
  float l_part[2] = {0.f, 0.f};
#pragma unroll
  for (int gi = 0; gi < 2; ++gi)
#pragma unroll
    for (int i = 0; i < 4; ++i) acco[gi][i] = f32x4{0, 0, 0, 0};

  // one u64 mask word per lane per gi per tile: row = q0+32w+16gi+c
  const u64* mrowp = Mp + ((size_t)b * S_ + q0 + 32 * w + c) * NKT;

  for (int kt = 0; kt < NKT; ++kt) {
    const char* cK = (const char*)sK[kt & 1];
    const char* cV = (const char*)sV[kt & 1];

    __syncthreads();   // single barrier: gll(kt) drained; prev-iter V reads done

    u64 mw[2];
    mw[0] = mrowp[kt];
    mw[1] = mrowp[16 * NKT + kt];

    // ---- scores: S^T = K Q^T (log2 domain via pre-scaled Q) ----
    // D[m=key_local][n=qrow]: lane holds qrow=c, keys 16n + 4*quad + r
    f32x4 accs[2][4];
#pragma unroll
    for (int n = 0; n < 4; ++n) {
      bf16x8 kb0 = *(bf16x8*)(cK + SW(16 * n + c, quad * 16));
      bf16x8 kb1 = *(bf16x8*)(cK + SW(16 * n + c, 64 + quad * 16));
#pragma unroll
      for (int gi = 0; gi < 2; ++gi) {
        f32x4 z = {0, 0, 0, 0};
        z = __builtin_amdgcn_mfma_f32_16x16x32_bf16(kb0, qa[gi][0], z, 0, 0, 0);
        z = __builtin_amdgcn_mfma_f32_16x16x32_bf16(kb1, qa[gi][1], z, 0, 0, 0);
        accs[gi][n] = z;
      }
    }

    // async prefetch tile kt+1: stays in flight through exp+PV, drained at next barrier.
    // Writes buffer (kt+1)&1 which no wave touches between the surrounding barriers.
    if (kt + 1 < NKT) {
      char* kn = (char*)sK[(kt + 1) & 1];
      char* vn = (char*)sV[(kt + 1) & 1];
      const char* kg = Kt + (size_t)(kt + 1) * 8192;
      const char* vg = Vt + (size_t)(kt + 1) * 8192;
#pragma unroll
      for (int j = 0; j < 2; ++j) {
        gll16(kg + tid * 16 + j * 4096, kn + tid * 16 + j * 4096);
        gll16(vg + tid * 16 + j * 4096, vn + tid * 16 + j * 4096);
      }
    }

    // ---- softmax numerator + in-register C->A transform ----
    bf16x8 pa[2][2];
#pragma unroll
    for (int gi = 0; gi < 2; ++gi) {
      u32 mlo = (u32)(mw[gi] >> (4 * quad));        // bits: n=0 -> r, n=1 -> 16+r
      u32 mhi = (u32)(mw[gi] >> (4 * quad + 32));   // bits: n=2 -> r, n=3 -> 16+r
      float e[4][4];
#pragma unroll
      for (int n = 0; n < 4; ++n) {
        u32 mword = (n < 2) ? mlo : mhi;
        int sh = 16 * (n & 1);
#pragma unroll
        for (int r = 0; r < 4; ++r)
          e[n][r] = ((mword >> (sh + r)) & 1u) ? exp2f(accs[gi][n][r]) : 0.0f;
      }
      l_part[gi] += ((e[0][0] + e[0][1]) + (e[0][2] + e[0][3]))
                  + ((e[1][0] + e[1][1]) + (e[1][2] + e[1][3]))
                  + ((e[2][0] + e[2][1]) + (e[2][2] + e[2][3]))
                  + ((e[3][0] + e[3][1]) + (e[3][2] + e[3][3]));

      // pack pairs: pk[n][h] = bf16(keys 16n+4quad+2h, +1)
      u32 pk[4][2];
#pragma unroll
      for (int n = 0; n < 4; ++n) {
        union { __hip_bfloat162 h; u32 u; } p0, p1;
        p0.h = __float22bfloat162_rn(make_float2(e[n][0], e[n][1]));
        p1.h = __float22bfloat162_rn(make_float2(e[n][2], e[n][3]));
        pk[n][0] = p0.u;
        pk[n][1] = p1.u;
      }

      // lane-routing network (vdst = even-n, vsrc = odd-n; see header comment)
#pragma unroll
      for (int t = 0; t < 2; ++t) {
        union { bf16x8 v; u32 uw[4]; } pu;
#pragma unroll
        for (int h = 0; h < 2; ++h) {
          u32 a  = pk[2 * t][h];       // vdst = X (n = 2t)
          u32 bq = pk[2 * t + 1][h];   // vsrc = Y (n = 2t+1)
          asm("v_permlane32_swap_b32 %0, %1" : "+v"(a), "+v"(bq));
          asm("v_permlane16_swap_b32 %0, %1" : "+v"(a), "+v"(bq));
          pu.uw[h]     = a;            // W_A: keys 32t + 8*quad + 2h, +1
          pu.uw[2 + h] = bq;           // W_B: keys 32t + 8*quad + 4 + 2h, +1
        }
        pa[gi][t] = pu.v;
      }
    }

    // ---- O += P V ----
#pragma unroll
    for (int dn = 0; dn < 4; ++dn) {
      bf16x8 vb0 = *(bf16x8*)(cV + SW(16 * dn + c, quad * 16));
      bf16x8 vb1 = *(bf16x8*)(cV + SW(16 * dn + c, 64 + quad * 16));
#pragma unroll
      for (int gi = 0; gi < 2; ++gi) {
        acco[gi][dn] = __builtin_amdgcn_mfma_f32_16x16x32_bf16(pa[gi][0], vb0, acco[gi][dn], 0, 0, 0);
        acco[gi][dn] = __builtin_amdgcn_mfma_f32_16x16x32_bf16(pa[gi][1], vb1, acco[gi][dn], 0, 0, 0);
      }
    }
  }

  // ---- epilogue: l lives at lane c (per q-row); reduce across quads, redistribute ----
#pragma unroll
  for (int gi = 0; gi < 2; ++gi) {
    float l = l_part[gi];
    l += __shfl_xor(l, 16);
    l += __shfl_xor(l, 32);
    float inv = 1.0f / l;
#pragma unroll
    for (int r = 0; r < 4; ++r) {
      // output row quad*4+r needs inv from the lane with c == quad*4+r (same quad group)
      float invr = __shfl(inv, (lane & 48) | (quad * 4 + r));
      size_t orow = base + (size_t)(q0 + 32 * w + 16 * gi + quad * 4 + r) * D_;
#pragma unroll
      for (int dn = 0; dn < 4; ++dn)
        Og[orow + 16 * dn + c] = acco[gi][dn][r] * invr;
    }
  }
}

extern "C" void kernel_launch(void* const* d_in, const int* in_sizes, int n_in,
                              void* d_out, int out_size, void* d_ws, size_t ws_size,
                              hipStream_t stream) {
  const float* Kg = (const float*)d_in[0];  // key
  const float* Qg = (const float*)d_in[1];  // query
  const float* Vg = (const float*)d_in[2];  // value
  const int*   Mg = (const int*)d_in[3];    // mask
  float* Og = (float*)d_out;

  char* ws  = (char*)d_ws;
  u64*  Mp  = (u64*)ws;                                  // 2 MiB
  char* Ksw = ws + (size_t)(2u << 20);                   // 16 MiB
  char* Vsw = ws + (size_t)(2u << 20) + (16u << 20);     // 16 MiB

  prepass<<<26624, 256, 0, stream>>>(Kg, Vg, Mg, Ksw, Vsw, Mp);
  attn_kernel<<<dim3(S_ / QM, B_ * H_), 256, 0, stream>>>(Qg, Ksw, Vsw, Mp, Og);
}

// Round 3
// 302.354 us; speedup vs baseline: 1.0597x; 1.0597x over previous
//
#include <hip/hip_runtime.h>
#include <hip/hip_bf16.h>
#include <stdint.h>

#define B_ 4
#define H_ 16
#define S_ 2048
#define D_ 64
#define NKT (S_ / 64)
#define QM 128

typedef __attribute__((ext_vector_type(8))) short bf16x8;
typedef __attribute__((ext_vector_type(4))) float f32x4;
typedef unsigned long long u64;
typedef unsigned int u32;

// hardware packed f32->bf16 (RNE). No builtin on gfx950 (m240) -> inline asm.
__device__ inline u32 cvt_pk_bf16(float lo, float hi) {
  u32 r;
  asm("v_cvt_pk_bf16_f32 %0, %1, %2" : "=v"(r) : "v"(lo), "v"(hi));
  return r;
}

// XOR-swizzled byte offset in a row x 128-byte tile image
__device__ inline int SW(int row, int byteoff) {
  return row * 128 + (byteoff ^ ((row & 7) << 4));
}

__device__ inline void gll16(const void* g, void* l) {
  __builtin_amdgcn_global_load_lds(
      (const __attribute__((address_space(1))) u32*)g,
      (__attribute__((address_space(3))) u32*)(uintptr_t)l, 16, 0, 0);
}

// ---------------- fused prepass ----------------
// blocks [0,8192):        K fp32 -> bf16 swizzled rows       (hw cvt_pk)
// blocks [8192,10240):    V fp32 -> bf16 transposed 64-key tiles (hw cvt_pk)
// blocks [10240,26624):   mask int32 -> packed u64 bits
__global__ __launch_bounds__(256)
void prepass(const float* __restrict__ Kg, const float* __restrict__ Vg,
             const int* __restrict__ Mg,
             char* __restrict__ Ksw, char* __restrict__ Vsw, u64* __restrict__ Mp) {
  __shared__ short tile[4096];
  const int bid = blockIdx.x, tid = threadIdx.x;
  if (bid < 8192) {
    int idx = bid * 256 + tid;
    int row = idx >> 4, c4 = idx & 15;
    float4 v = *(const float4*)(Kg + (size_t)idx * 4);
    uint2 u;
    u.x = cvt_pk_bf16(v.x, v.y);
    u.y = cvt_pk_bf16(v.z, v.w);
    *(uint2*)(Ksw + (size_t)row * 128 + ((c4 * 8) ^ ((row & 7) << 4))) = u;
  } else if (bid < 10240) {
    int vb = bid - 8192;
    char* ct = (char*)tile;
    int c4 = tid & 15, g = tid >> 4;
    const float* src = Vg + (size_t)vb * (64 * D_) + (size_t)(g * 4) * D_ + c4 * 4;
    float4 vv[4];
#pragma unroll
    for (int i = 0; i < 4; ++i) vv[i] = *(const float4*)(src + (size_t)i * D_);
    const float* vf = (const float*)vv;
#pragma unroll
    for (int dd = 0; dd < 4; ++dd) {
      uint2 u;
      u.x = cvt_pk_bf16(vf[0 * 4 + dd], vf[1 * 4 + dd]);
      u.y = cvt_pk_bf16(vf[2 * 4 + dd], vf[3 * 4 + dd]);
      *(uint2*)(ct + SW(c4 * 4 + dd, g * 8)) = u;
    }
    __syncthreads();
    char* dst = Vsw + (size_t)vb * 8192;
#pragma unroll
    for (int j = 0; j < 2; ++j)
      *(float4*)(dst + tid * 16 + j * 4096) = *(const float4*)(ct + tid * 16 + j * 4096);
  } else {
    int pb = bid - 10240;
    int gbase = pb * 1024;
#pragma unroll
    for (int j = 0; j < 4; ++j) {
      int idx = gbase + j * 256 + tid;
      u64 bits = __ballot(Mg[idx] != 0);
      if ((tid & 63) == 0) Mp[idx >> 6] = bits;
    }
  }
}

// ---------------- main kernel ----------------
// Swapped-operand QK^T (S^T); in-register P->A transform via asm cvt_pk +
// permlane32/16 swaps (verified round 2). New this round:
//  - l computed by MFMA ones-column: acc_l = mfma(pa, B=1, acc_l) -> D[q][*]=sum_k P,
//    landing on exactly the (quad*4+r) rows this lane stores; no sum tree, no shuffles.
//  - kt loop unrolled x2 with constexpr buffer parity: ds addresses loop-invariant,
//    parity folds into ds offset immediates.
//  - XCD swizzle: all 16 q-blocks of a bh on one XCD (flat%8 preserved).
//  - s_setprio(1) around MFMA clusters (T5).
__global__ __launch_bounds__(256, 4)
void attn_kernel(const float* __restrict__ Qg,
                 const char* __restrict__ Ksw,
                 const char* __restrict__ Vsw,
                 const u64* __restrict__ Mp,
                 float* __restrict__ Og) {
  __shared__ short sK[2][4096];
  __shared__ short sV[2][4096];

  const int tid  = threadIdx.x;
  const int w    = tid >> 6;
  const int lane = tid & 63;
  const int quad = lane >> 4;
  const int c    = lane & 15;

  // XCD swizzle: flat id's %8 decides XCD (round-robin). Keep all 16 q-chunks of
  // one bh on the same XCD: bh = (flat&7) | ((flat>>7)<<3), qi = (flat>>3)&15.
  const int flat = blockIdx.x + (int)gridDim.x * blockIdx.y;   // gridDim.x == 16
  const int bh   = (flat & 7) | ((flat >> 7) << 3);
  const int q0   = ((flat >> 3) & 15) * QM;
  const int b    = bh >> 4;            // H_ == 16

  const size_t base = (size_t)bh * (S_ * D_);
  const char* Kt = Ksw + (size_t)bh * (S_ * 128);
  const char* Vt = Vsw + (size_t)bh * (S_ * 128);
  char* cK0 = (char*)sK;               // 16 KB contiguous, doubles as Q stage

  // ---- stage Q (pre-scaled into log2 domain) into the sK area ----
  const float SC = 0.125f * 1.44269504088896f;   // 1/sqrt(64) * log2(e)
#pragma unroll
  for (int j = 0; j < 8; ++j) {
    int idx = tid + j * 256;
    int row = idx >> 4, c4 = idx & 15;
    float4 v = *(const float4*)(Qg + base + (size_t)(q0 + row) * D_ + c4 * 4);
    uint2 u;
    u.x = cvt_pk_bf16(v.x * SC, v.y * SC);
    u.y = cvt_pk_bf16(v.z * SC, v.w * SC);
    *(uint2*)(cK0 + SW(row, c4 * 8)) = u;
  }
  __syncthreads();
  bf16x8 qa[2][2];
#pragma unroll
  for (int gi = 0; gi < 2; ++gi) {
    qa[gi][0] = *(bf16x8*)(cK0 + SW(32 * w + 16 * gi + c, quad * 16));
    qa[gi][1] = *(bf16x8*)(cK0 + SW(32 * w + 16 * gi + c, 64 + quad * 16));
  }
  __syncthreads();   // all Q reads done; sK area may now be overwritten

  // issue tile-0 async staging
#pragma unroll
  for (int j = 0; j < 2; ++j) {
    gll16(Kt + tid * 16 + j * 4096, (char*)sK[0] + tid * 16 + j * 4096);
    gll16(Vt + tid * 16 + j * 4096, (char*)sV[0] + tid * 16 + j * 4096);
  }

  // loop-invariant swizzled ds offsets (same formula serves K and V reads)
  int koff[4][2];
#pragma unroll
  for (int n = 0; n < 4; ++n) {
    koff[n][0] = SW(16 * n + c, quad * 16);
    koff[n][1] = SW(16 * n + c, 64 + quad * 16);
  }

  // all-ones bf16 B operand for the l column (layout-free: every element 1.0)
  bf16x8 ones;
#pragma unroll
  for (int i = 0; i < 8; ++i) ones[i] = (short)0x3F80;

  f32x4 acco[2][4];
  f32x4 acc_l[2];
#pragma unroll
  for (int gi = 0; gi < 2; ++gi) {
    acc_l[gi] = f32x4{0, 0, 0, 0};
#pragma unroll
    for (int i = 0; i < 4; ++i) acco[gi][i] = f32x4{0, 0, 0, 0};
  }

  // one u64 mask word per lane per gi per tile: row = q0+32w+16gi+c
  const u64* mrowp = Mp + ((size_t)b * S_ + q0 + 32 * w + c) * NKT;

  const char* kbase = (const char*)sK;
  const char* vbase = (const char*)sV;

  for (int kt2 = 0; kt2 < NKT; kt2 += 2) {
#pragma unroll
    for (int p = 0; p < 2; ++p) {
      const int kt = kt2 + p;

      __syncthreads();   // gll(kt) drained; prev-iter V reads done

      u64 mw[2];
      mw[0] = mrowp[kt];
      mw[1] = mrowp[16 * NKT + kt];

      // ---- scores: S^T = K Q^T (lane holds qrow=c, keys 16n + 4*quad + r) ----
      f32x4 accs[2][4];
      __builtin_amdgcn_s_setprio(1);
#pragma unroll
      for (int n = 0; n < 4; ++n) {
        bf16x8 kb0 = *(bf16x8*)(kbase + koff[n][0] + p * 8192);
        bf16x8 kb1 = *(bf16x8*)(kbase + koff[n][1] + p * 8192);
#pragma unroll
        for (int gi = 0; gi < 2; ++gi) {
          f32x4 z = {0, 0, 0, 0};
          z = __builtin_amdgcn_mfma_f32_16x16x32_bf16(kb0, qa[gi][0], z, 0, 0, 0);
          z = __builtin_amdgcn_mfma_f32_16x16x32_bf16(kb1, qa[gi][1], z, 0, 0, 0);
          accs[gi][n] = z;
        }
      }
      __builtin_amdgcn_s_setprio(0);

      // async prefetch tile kt+1 into parity p^1; in flight through exp+PV,
      // drained at the next barrier.
      if (kt + 1 < NKT) {
        char* kn = (char*)sK + (p ^ 1) * 8192;
        char* vn = (char*)sV + (p ^ 1) * 8192;
        const char* kg = Kt + (size_t)(kt + 1) * 8192;
        const char* vg = Vt + (size_t)(kt + 1) * 8192;
#pragma unroll
        for (int j = 0; j < 2; ++j) {
          gll16(kg + tid * 16 + j * 4096, kn + tid * 16 + j * 4096);
          gll16(vg + tid * 16 + j * 4096, vn + tid * 16 + j * 4096);
        }
      }

      // ---- softmax numerator + in-register C->A transform ----
      bf16x8 pa[2][2];
#pragma unroll
      for (int gi = 0; gi < 2; ++gi) {
        u32 mlo = (u32)(mw[gi] >> (4 * quad));        // bits: n=0 -> r, n=1 -> 16+r
        u32 mhi = (u32)(mw[gi] >> (4 * quad + 32));   // bits: n=2 -> r, n=3 -> 16+r
        float e[4][4];
#pragma unroll
        for (int n = 0; n < 4; ++n) {
          u32 mword = (n < 2) ? mlo : mhi;
          int sh = 16 * (n & 1);
#pragma unroll
          for (int r = 0; r < 4; ++r) {
            float sm = ((mword >> (sh + r)) & 1u) ? accs[gi][n][r] : -1000.0f;
            e[n][r] = exp2f(sm);                       // bare v_exp_f32; exp2(-1000)=+0
          }
        }

        // pack pairs: pk[n][h] = bf16(keys 16n+4quad+2h, +1)
        u32 pk[4][2];
#pragma unroll
        for (int n = 0; n < 4; ++n) {
          pk[n][0] = cvt_pk_bf16(e[n][0], e[n][1]);
          pk[n][1] = cvt_pk_bf16(e[n][2], e[n][3]);
        }

        // lane-routing network (vdst = even-n, vsrc = odd-n; verified round 2)
#pragma unroll
        for (int t = 0; t < 2; ++t) {
          union { bf16x8 v; u32 uw[4]; } pu;
#pragma unroll
          for (int h = 0; h < 2; ++h) {
            u32 a  = pk[2 * t][h];       // vdst = X (n = 2t)
            u32 bq = pk[2 * t + 1][h];   // vsrc = Y (n = 2t+1)
            asm("v_permlane32_swap_b32 %0, %1" : "+v"(a), "+v"(bq));
            asm("v_permlane16_swap_b32 %0, %1" : "+v"(a), "+v"(bq));
            pu.uw[h]     = a;            // W_A: keys 32t + 8*quad + 2h, +1
            pu.uw[2 + h] = bq;           // W_B: keys 32t + 8*quad + 4 + 2h, +1
          }
          pa[gi][t] = pu.v;
        }
      }

      // ---- O += P V ; l += P · 1 (ones-column MFMA) ----
      __builtin_amdgcn_s_setprio(1);
#pragma unroll
      for (int dn = 0; dn < 4; ++dn) {
        bf16x8 vb0 = *(bf16x8*)(vbase + koff[dn][0] + p * 8192);
        bf16x8 vb1 = *(bf16x8*)(vbase + koff[dn][1] + p * 8192);
#pragma unroll
        for (int gi = 0; gi < 2; ++gi) {
          acco[gi][dn] = __builtin_amdgcn_mfma_f32_16x16x32_bf16(pa[gi][0], vb0, acco[gi][dn], 0, 0, 0);
          acco[gi][dn] = __builtin_amdgcn_mfma_f32_16x16x32_bf16(pa[gi][1], vb1, acco[gi][dn], 0, 0, 0);
        }
      }
#pragma unroll
      for (int gi = 0; gi < 2; ++gi) {
        acc_l[gi] = __builtin_amdgcn_mfma_f32_16x16x32_bf16(pa[gi][0], ones, acc_l[gi], 0, 0, 0);
        acc_l[gi] = __builtin_amdgcn_mfma_f32_16x16x32_bf16(pa[gi][1], ones, acc_l[gi], 0, 0, 0);
      }
      __builtin_amdgcn_s_setprio(0);
    }
  }

  // ---- epilogue: acc_l[gi][r] is l for exactly the row this lane stores ----
#pragma unroll
  for (int gi = 0; gi < 2; ++gi) {
#pragma unroll
    for (int r = 0; r < 4; ++r) {
      float inv = 1.0f / acc_l[gi][r];
      size_t orow = base + (size_t)(q0 + 32 * w + 16 * gi + quad * 4 + r) * D_;
#pragma unroll
      for (int dn = 0; dn < 4; ++dn)
        Og[orow + 16 * dn + c] = acco[gi][dn][r] * inv;
    }
  }
}

extern "C" void kernel_launch(void* const* d_in, const int* in_sizes, int n_in,
                              void* d_out, int out_size, void* d_ws, size_t ws_size,
                              hipStream_t stream) {
  const float* Kg = (const float*)d_in[0];  // key
  const float* Qg = (const float*)d_in[1];  // query
  const float* Vg = (const float*)d_in[2];  // value
  const int*   Mg = (const int*)d_in[3];    // mask
  float* Og = (float*)d_out;

  char* ws  = (char*)d_ws;
  u64*  Mp  = (u64*)ws;                                  // 2 MiB
  char* Ksw = ws + (size_t)(2u << 20);                   // 16 MiB
  char* Vsw = ws + (size_t)(2u << 20) + (16u << 20);     // 16 MiB

  prepass<<<26624, 256, 0, stream>>>(Kg, Vg, Mg, Ksw, Vsw, Mp);
  attn_kernel<<<dim3(S_ / QM, B_ * H_), 256, 0, stream>>>(Qg, Ksw, Vsw, Mp, Og);
}

// Round 5
// 300.472 us; speedup vs baseline: 1.0663x; 1.0063x over previous
//
#include <hip/hip_runtime.h>
#include <hip/hip_bf16.h>
#include <stdint.h>

#define B_ 4
#define H_ 16
#define S_ 2048
#define D_ 64
#define NKT (S_ / 64)
#define QM 128

typedef __attribute__((ext_vector_type(8))) short bf16x8;
typedef __attribute__((ext_vector_type(4))) float f32x4;
typedef unsigned long long u64;
typedef unsigned int u32;

// hardware packed f32->bf16 (RNE). No builtin on gfx950 (m240) -> inline asm.
__device__ inline u32 cvt_pk_bf16(float lo, float hi) {
  u32 r;
  asm("v_cvt_pk_bf16_f32 %0, %1, %2" : "=v"(r) : "v"(lo), "v"(hi));
  return r;
}

// XOR-swizzled byte offset in a row x 128-byte tile image
__device__ inline int SW(int row, int byteoff) {
  return row * 128 + (byteoff ^ ((row & 7) << 4));
}

__device__ inline void gll16(const void* g, void* l) {
  __builtin_amdgcn_global_load_lds(
      (const __attribute__((address_space(1))) u32*)g,
      (__attribute__((address_space(3))) u32*)(uintptr_t)l, 16, 0, 0);
}

// ---------------- prepass kernel 1: K fp32 -> bf16 swizzled rows ----------------
// Per thread: 32B fp32 in -> 16B bf16 out. Swizzle is 16B-granular so the
// uint4 store stays contiguous (XOR touches only bits 4-6). Layout identical
// to the round-3 fused version (two adjacent 8B stores == one 16B store).
__global__ __launch_bounds__(256)
void prep_k(const float* __restrict__ Kg, char* __restrict__ Ksw) {
  int idx8 = blockIdx.x * 256 + threadIdx.x;     // 16B-chunk index
  int row = idx8 >> 3, c8 = idx8 & 7;
  const float* src = Kg + (size_t)idx8 * 8;
  float4 v0 = *(const float4*)src;
  float4 v1 = *(const float4*)(src + 4);
  uint4 u;
  u.x = cvt_pk_bf16(v0.x, v0.y);
  u.y = cvt_pk_bf16(v0.z, v0.w);
  u.z = cvt_pk_bf16(v1.x, v1.y);
  u.w = cvt_pk_bf16(v1.z, v1.w);
  *(uint4*)(Ksw + (size_t)row * 128 + ((c8 * 16) ^ ((row & 7) << 4))) = u;
}

// ---------------- prepass kernel 2: V fp32 -> bf16 transposed 64-key tiles ----------------
__global__ __launch_bounds__(256)
void prep_v(const float* __restrict__ Vg, char* __restrict__ Vsw) {
  __shared__ short tile[4096];
  const int vb = blockIdx.x, tid = threadIdx.x;
  char* ct = (char*)tile;
  int c4 = tid & 15, g = tid >> 4;
  const float* src = Vg + (size_t)vb * (64 * D_) + (size_t)(g * 4) * D_ + c4 * 4;
  float4 vv[4];
#pragma unroll
  for (int i = 0; i < 4; ++i) vv[i] = *(const float4*)(src + (size_t)i * D_);
  const float* vf = (const float*)vv;
#pragma unroll
  for (int dd = 0; dd < 4; ++dd) {
    uint2 u;
    u.x = cvt_pk_bf16(vf[0 * 4 + dd], vf[1 * 4 + dd]);
    u.y = cvt_pk_bf16(vf[2 * 4 + dd], vf[3 * 4 + dd]);
    *(uint2*)(ct + SW(c4 * 4 + dd, g * 8)) = u;
  }
  __syncthreads();
  char* dst = Vsw + (size_t)vb * 8192;
#pragma unroll
  for (int j = 0; j < 2; ++j)
    *(float4*)(dst + tid * 16 + j * 4096) = *(const float4*)(ct + tid * 16 + j * 4096);
}

// ---------------- prepass kernel 3: mask int32 -> packed u64 bits ----------------
// Per wave-chunk: 4 coalesced 256B loads -> 4 ballots -> one 32B store (lane 0).
// Word mapping Mp[chunk*4+j] <-> elements (chunk*4+j)*64 matches Mp[idx>>6].
__global__ __launch_bounds__(256)
void prep_m(const int* __restrict__ Mg, u64* __restrict__ Mp) {
  const int tid = threadIdx.x;
  const int lane = tid & 63;
  const int gwave = blockIdx.x * 4 + (tid >> 6);   // 4096 waves total
  for (int chunk = gwave; chunk < (B_ * S_ * S_ / 256); chunk += 4096) {
    const int* src = Mg + (size_t)chunk * 256;
    u64 bits[4];
#pragma unroll
    for (int j = 0; j < 4; ++j) bits[j] = __ballot(src[j * 64 + lane] != 0);
    if (lane == 0) {
      ulonglong4 o;
      o.x = bits[0]; o.y = bits[1]; o.z = bits[2]; o.w = bits[3];
      *(ulonglong4*)(Mp + (size_t)chunk * 4) = o;
    }
  }
}

// ---------------- main kernel (EXACT round-3 text; exp2f, not the builtin) ----------------
// Swapped-operand QK^T (S^T); in-register P->A transform via asm cvt_pk +
// permlane32/16 swaps (verified round 2). l via MFMA ones-column (verified
// round 3). kt loop unrolled x2 (constexpr buffer parity). XCD swizzle keeps
// all 16 q-blocks of one bh on the same XCD (FETCH 148->41MB, verified round 3).
__global__ __launch_bounds__(256, 4)
void attn_kernel(const float* __restrict__ Qg,
                 const char* __restrict__ Ksw,
                 const char* __restrict__ Vsw,
                 const u64* __restrict__ Mp,
                 float* __restrict__ Og) {
  __shared__ short sK[2][4096];
  __shared__ short sV[2][4096];

  const int tid  = threadIdx.x;
  const int w    = tid >> 6;
  const int lane = tid & 63;
  const int quad = lane >> 4;
  const int c    = lane & 15;

  // XCD swizzle: flat%8 decides XCD. bh = (flat&7) | ((flat>>7)<<3), qi = (flat>>3)&15.
  const int flat = blockIdx.x + (int)gridDim.x * blockIdx.y;   // gridDim.x == 16
  const int bh   = (flat & 7) | ((flat >> 7) << 3);
  const int q0   = ((flat >> 3) & 15) * QM;
  const int b    = bh >> 4;            // H_ == 16

  const size_t base = (size_t)bh * (S_ * D_);
  const char* Kt = Ksw + (size_t)bh * (S_ * 128);
  const char* Vt = Vsw + (size_t)bh * (S_ * 128);
  char* cK0 = (char*)sK;               // 16 KB contiguous, doubles as Q stage

  // ---- stage Q (pre-scaled into log2 domain) into the sK area ----
  const float SC = 0.125f * 1.44269504088896f;   // 1/sqrt(64) * log2(e)
#pragma unroll
  for (int j = 0; j < 8; ++j) {
    int idx = tid + j * 256;
    int row = idx >> 4, c4 = idx & 15;
    float4 v = *(const float4*)(Qg + base + (size_t)(q0 + row) * D_ + c4 * 4);
    uint2 u;
    u.x = cvt_pk_bf16(v.x * SC, v.y * SC);
    u.y = cvt_pk_bf16(v.z * SC, v.w * SC);
    *(uint2*)(cK0 + SW(row, c4 * 8)) = u;
  }
  __syncthreads();
  bf16x8 qa[2][2];
#pragma unroll
  for (int gi = 0; gi < 2; ++gi) {
    qa[gi][0] = *(bf16x8*)(cK0 + SW(32 * w + 16 * gi + c, quad * 16));
    qa[gi][1] = *(bf16x8*)(cK0 + SW(32 * w + 16 * gi + c, 64 + quad * 16));
  }
  __syncthreads();   // all Q reads done; sK area may now be overwritten

  // issue tile-0 async staging
#pragma unroll
  for (int j = 0; j < 2; ++j) {
    gll16(Kt + tid * 16 + j * 4096, (char*)sK[0] + tid * 16 + j * 4096);
    gll16(Vt + tid * 16 + j * 4096, (char*)sV[0] + tid * 16 + j * 4096);
  }

  // loop-invariant swizzled ds offsets (same formula serves K and V reads)
  int koff[4][2];
#pragma unroll
  for (int n = 0; n < 4; ++n) {
    koff[n][0] = SW(16 * n + c, quad * 16);
    koff[n][1] = SW(16 * n + c, 64 + quad * 16);
  }

  // all-ones bf16 B operand for the l column (layout-free: every element 1.0)
  bf16x8 ones;
#pragma unroll
  for (int i = 0; i < 8; ++i) ones[i] = (short)0x3F80;

  f32x4 acco[2][4];
  f32x4 acc_l[2];
#pragma unroll
  for (int gi = 0; gi < 2; ++gi) {
    acc_l[gi] = f32x4{0, 0, 0, 0};
#pragma unroll
    for (int i = 0; i < 4; ++i) acco[gi][i] = f32x4{0, 0, 0, 0};
  }

  // one u64 mask word per lane per gi per tile: row = q0+32w+16gi+c
  const u64* mrowp = Mp + ((size_t)b * S_ + q0 + 32 * w + c) * NKT;

  const char* kbase = (const char*)sK;
  const char* vbase = (const char*)sV;

  for (int kt2 = 0; kt2 < NKT; kt2 += 2) {
#pragma unroll
    for (int p = 0; p < 2; ++p) {
      const int kt = kt2 + p;

      __syncthreads();   // gll(kt) drained; prev-iter V reads done

      u64 mw[2];
      mw[0] = mrowp[kt];
      mw[1] = mrowp[16 * NKT + kt];

      // ---- scores: S^T = K Q^T (lane holds qrow=c, keys 16n + 4*quad + r) ----
      f32x4 accs[2][4];
      __builtin_amdgcn_s_setprio(1);
#pragma unroll
      for (int n = 0; n < 4; ++n) {
        bf16x8 kb0 = *(bf16x8*)(kbase + koff[n][0] + p * 8192);
        bf16x8 kb1 = *(bf16x8*)(kbase + koff[n][1] + p * 8192);
#pragma unroll
        for (int gi = 0; gi < 2; ++gi) {
          f32x4 z = {0, 0, 0, 0};
          z = __builtin_amdgcn_mfma_f32_16x16x32_bf16(kb0, qa[gi][0], z, 0, 0, 0);
          z = __builtin_amdgcn_mfma_f32_16x16x32_bf16(kb1, qa[gi][1], z, 0, 0, 0);
          accs[gi][n] = z;
        }
      }
      __builtin_amdgcn_s_setprio(0);

      // async prefetch tile kt+1 into parity p^1; in flight through exp+PV,
      // drained at the next barrier.
      if (kt + 1 < NKT) {
        char* kn = (char*)sK + (p ^ 1) * 8192;
        char* vn = (char*)sV + (p ^ 1) * 8192;
        const char* kg = Kt + (size_t)(kt + 1) * 8192;
        const char* vg = Vt + (size_t)(kt + 1) * 8192;
#pragma unroll
        for (int j = 0; j < 2; ++j) {
          gll16(kg + tid * 16 + j * 4096, kn + tid * 16 + j * 4096);
          gll16(vg + tid * 16 + j * 4096, vn + tid * 16 + j * 4096);
        }
      }

      // ---- softmax numerator + in-register C->A transform ----
      bf16x8 pa[2][2];
#pragma unroll
      for (int gi = 0; gi < 2; ++gi) {
        u32 mlo = (u32)(mw[gi] >> (4 * quad));        // bits: n=0 -> r, n=1 -> 16+r
        u32 mhi = (u32)(mw[gi] >> (4 * quad + 32));   // bits: n=2 -> r, n=3 -> 16+r
        float e[4][4];
#pragma unroll
        for (int n = 0; n < 4; ++n) {
          u32 mword = (n < 2) ? mlo : mhi;
          int sh = 16 * (n & 1);
#pragma unroll
          for (int r = 0; r < 4; ++r) {
            float sm = ((mword >> (sh + r)) & 1u) ? accs[gi][n][r] : -1000.0f;
            e[n][r] = exp2f(sm);                       // bare v_exp_f32; exp2(-1000)=+0
          }
        }

        // pack pairs: pk[n][h] = bf16(keys 16n+4quad+2h, +1)
        u32 pk[4][2];
#pragma unroll
        for (int n = 0; n < 4; ++n) {
          pk[n][0] = cvt_pk_bf16(e[n][0], e[n][1]);
          pk[n][1] = cvt_pk_bf16(e[n][2], e[n][3]);
        }

        // lane-routing network (vdst = even-n, vsrc = odd-n; verified round 2)
#pragma unroll
        for (int t = 0; t < 2; ++t) {
          union { bf16x8 v; u32 uw[4]; } pu;
#pragma unroll
          for (int h = 0; h < 2; ++h) {
            u32 a  = pk[2 * t][h];       // vdst = X (n = 2t)
            u32 bq = pk[2 * t + 1][h];   // vsrc = Y (n = 2t+1)
            asm("v_permlane32_swap_b32 %0, %1" : "+v"(a), "+v"(bq));
            asm("v_permlane16_swap_b32 %0, %1" : "+v"(a), "+v"(bq));
            pu.uw[h]     = a;            // W_A: keys 32t + 8*quad + 2h, +1
            pu.uw[2 + h] = bq;           // W_B: keys 32t + 8*quad + 4 + 2h, +1
          }
          pa[gi][t] = pu.v;
        }
      }

      // ---- O += P V ; l += P · 1 (ones-column MFMA) ----
      __builtin_amdgcn_s_setprio(1);
#pragma unroll
      for (int dn = 0; dn < 4; ++dn) {
        bf16x8 vb0 = *(bf16x8*)(vbase + koff[dn][0] + p * 8192);
        bf16x8 vb1 = *(bf16x8*)(vbase + koff[dn][1] + p * 8192);
#pragma unroll
        for (int gi = 0; gi < 2; ++gi) {
          acco[gi][dn] = __builtin_amdgcn_mfma_f32_16x16x32_bf16(pa[gi][0], vb0, acco[gi][dn], 0, 0, 0);
          acco[gi][dn] = __builtin_amdgcn_mfma_f32_16x16x32_bf16(pa[gi][1], vb1, acco[gi][dn], 0, 0, 0);
        }
      }
#pragma unroll
      for (int gi = 0; gi < 2; ++gi) {
        acc_l[gi] = __builtin_amdgcn_mfma_f32_16x16x32_bf16(pa[gi][0], ones, acc_l[gi], 0, 0, 0);
        acc_l[gi] = __builtin_amdgcn_mfma_f32_16x16x32_bf16(pa[gi][1], ones, acc_l[gi], 0, 0, 0);
      }
      __builtin_amdgcn_s_setprio(0);
    }
  }

  // ---- epilogue: acc_l[gi][r] is l for exactly the row this lane stores ----
#pragma unroll
  for (int gi = 0; gi < 2; ++gi) {
#pragma unroll
    for (int r = 0; r < 4; ++r) {
      float inv = 1.0f / acc_l[gi][r];
      size_t orow = base + (size_t)(q0 + 32 * w + 16 * gi + quad * 4 + r) * D_;
#pragma unroll
      for (int dn = 0; dn < 4; ++dn)
        Og[orow + 16 * dn + c] = acco[gi][dn][r] * inv;
    }
  }
}

extern "C" void kernel_launch(void* const* d_in, const int* in_sizes, int n_in,
                              void* d_out, int out_size, void* d_ws, size_t ws_size,
                              hipStream_t stream) {
  const float* Kg = (const float*)d_in[0];  // key
  const float* Qg = (const float*)d_in[1];  // query
  const float* Vg = (const float*)d_in[2];  // value
  const int*   Mg = (const int*)d_in[3];    // mask
  float* Og = (float*)d_out;

  char* ws  = (char*)d_ws;
  u64*  Mp  = (u64*)ws;                                  // 2 MiB
  char* Ksw = ws + (size_t)(2u << 20);                   // 16 MiB
  char* Vsw = ws + (size_t)(2u << 20) + (16u << 20);     // 16 MiB

  prep_k<<<4096, 256, 0, stream>>>(Kg, Ksw);
  prep_v<<<2048, 256, 0, stream>>>(Vg, Vsw);
  prep_m<<<1024, 256, 0, stream>>>(Mg, Mp);
  attn_kernel<<<dim3(S_ / QM, B_ * H_), 256, 0, stream>>>(Qg, Ksw, Vsw, Mp, Og);
}